// Round 1
// baseline (127.180 us; speedup 1.0000x reference)
//
#include <hip/hip_runtime.h>

// Problem constants (hardcoded in the reference)
#define NPIX 65536   // 256*256 = 2^16
#define KK   361     // 19*19
#define LSZ  19
#define HWD  256

// ---------------------------------------------------------------------------
// P1: rcpS1[p] = 1 / sum_s ker[s*NPIX + p]   (column sums of K x N matrix)
// ---------------------------------------------------------------------------
__global__ __launch_bounds__(256) void k_s1(const float* __restrict__ ker,
                                            float* __restrict__ rcpS1) {
    int p = blockIdx.x * blockDim.x + threadIdx.x;
    const float* kp = ker + p;
    float a0 = 0.f, a1 = 0.f, a2 = 0.f, a3 = 0.f;
    int s = 0;
    for (; s + 4 <= KK; s += 4) {
        a0 += kp[(size_t)(s + 0) * NPIX];
        a1 += kp[(size_t)(s + 1) * NPIX];
        a2 += kp[(size_t)(s + 2) * NPIX];
        a3 += kp[(size_t)(s + 3) * NPIX];
    }
    for (; s < KK; ++s) a0 += kp[(size_t)s * NPIX];
    rcpS1[p] = 1.0f / (a0 + a1 + a2 + a3);
}

// ---------------------------------------------------------------------------
// P3: fused  (a) scale by rcpS1[(q*K+t) & 0xFFFF]
//            (b) exact per-row sum -> rcpS2 (in-LDS, no atomics)
//            (c) scale by rcpS2[q]
//            (d) transpose N x K -> K x N:  flat2[t*N + q] = val
// One block = 32 consecutive rows q (a contiguous 46.2 KB slab of ker).
// ---------------------------------------------------------------------------
#define TQ 32
__global__ __launch_bounds__(256) void k_transpose(const float* __restrict__ ker,
                                                   const float* __restrict__ rcpS1,
                                                   float* __restrict__ flat2,
                                                   float* __restrict__ rcpS2) {
    __shared__ float tile[TQ * KK];   // 46,208 B
    __shared__ float rowrcp[TQ];
    const int tid = threadIdx.x;
    const int q0  = blockIdx.x * TQ;
    const int base = q0 * KK;         // fits in int (max ~23.6M)

    // load contiguous slab, scale by rcpS1
    for (int idx = tid; idx < TQ * KK; idx += 256) {
        int m = base + idx;
        tile[idx] = ker[m] * rcpS1[m & (NPIX - 1)];
    }
    __syncthreads();

    // exact row sums: 8 lanes per row, shuffle-reduce within the 8-group
    {
        int row = tid >> 3;
        int e0  = tid & 7;
        float acc = 0.f;
        for (int e = e0; e < KK; e += 8) acc += tile[row * KK + e];
        acc += __shfl_xor(acc, 1);
        acc += __shfl_xor(acc, 2);
        acc += __shfl_xor(acc, 4);
        if (e0 == 0) {
            float r = 1.0f / acc;
            rowrcp[row] = r;
            rcpS2[q0 + row] = r;
        }
    }
    __syncthreads();

    // transposed write: lanes vary along q (contiguous 128B segments)
    {
        int iq = tid & 31;
        int t0 = tid >> 5;   // 0..7
        float rr = rowrcp[iq];
        for (int t = t0; t < KK; t += 8) {
            flat2[(size_t)t * NPIX + q0 + iq] = tile[iq * KK + t] * rr;
        }
    }
}

// reflect-pad index (pad=9, size 256, mode="reflect" no edge repeat)
__device__ __forceinline__ int refl(int v) {
    v -= 9;
    v = v < 0 ? -v : v;
    v = v > 255 ? 510 - v : v;
    return v;
}

// ---------------------------------------------------------------------------
// P4: out[r] = (sum_u dg[r,u]*flat2[r*K+u]) / (sum_u flat2[r*K+u])
// One 64-lane wave per output row; 4 rows per 256-thread block.
// ---------------------------------------------------------------------------
__global__ __launch_bounds__(256) void k_out(const float* __restrict__ flat2,
                                             const float* __restrict__ in2,
                                             float* __restrict__ out) {
    int lane = threadIdx.x & 63;
    int r = blockIdx.x * 4 + (threadIdx.x >> 6);
    const float* row = flat2 + (size_t)r * KK;
    float vsum = 0.f, vdot = 0.f;
    for (int u = lane; u < KK; u += 64) {
        float v = row[u];
        int jj = r * KK + u;          // < 2^25, int ok
        int s  = jj >> 16;            // unf row (a,b)
        int c  = jj & (NPIX - 1);     // unf col (y,x)
        int y = c >> 8, x = c & 255;
        int a = s / LSZ, b = s - a * LSZ;
        float d = in2[refl(y + a) * HWD + refl(x + b)];
        vsum += v;
        vdot += d * v;
    }
    for (int m = 1; m < 64; m <<= 1) {
        vsum += __shfl_xor(vsum, m);
        vdot += __shfl_xor(vdot, m);
    }
    if (lane == 0) out[r] = vdot / vsum;
}

// ---------------------------------------------------------------------------
// Fallback (ws too small to hold the 90.3 MB transpose): strided gathers.
// ---------------------------------------------------------------------------
__global__ __launch_bounds__(256) void k_s2_fallback(const float* __restrict__ ker,
                                                     const float* __restrict__ rcpS1,
                                                     float* __restrict__ rcpS2) {
    int lane = threadIdx.x & 63;
    int q = blockIdx.x * 4 + (threadIdx.x >> 6);
    int base = q * KK;
    float acc = 0.f;
    for (int t = lane; t < KK; t += 64)
        acc += ker[base + t] * rcpS1[(base + t) & (NPIX - 1)];
    for (int m = 1; m < 64; m <<= 1) acc += __shfl_xor(acc, m);
    if (lane == 0) rcpS2[q] = 1.0f / acc;
}

__global__ __launch_bounds__(256) void k_out_fallback(const float* __restrict__ ker,
                                                      const float* __restrict__ rcpS1,
                                                      const float* __restrict__ rcpS2,
                                                      const float* __restrict__ in2,
                                                      float* __restrict__ out) {
    int lane = threadIdx.x & 63;
    int r = blockIdx.x * 4 + (threadIdx.x >> 6);
    float vsum = 0.f, vdot = 0.f;
    for (int u = lane; u < KK; u += 64) {
        int jj = r * KK + u;
        int t  = jj >> 16;
        int q  = jj & (NPIX - 1);
        int m  = q * KK + t;
        float v = ker[m] * rcpS1[m & (NPIX - 1)] * rcpS2[q];
        int s = jj >> 16;      // note: same decomposition feeds dg via unf layout
        int c = jj & (NPIX - 1);
        // dg uses jj = r*K+u -> row s=jj>>16 of unf, col c=jj&0xFFFF
        int y = c >> 8, x = c & 255;
        int a = s / LSZ, b = s - a * LSZ;
        float d = in2[refl(y + a) * HWD + refl(x + b)];
        vsum += v;
        vdot += d * v;
    }
    for (int mm = 1; mm < 64; mm <<= 1) {
        vsum += __shfl_xor(vsum, mm);
        vdot += __shfl_xor(vdot, mm);
    }
    if (lane == 0) out[r] = vdot / vsum;
}

extern "C" void kernel_launch(void* const* d_in, const int* in_sizes, int n_in,
                              void* d_out, int out_size, void* d_ws, size_t ws_size,
                              hipStream_t stream) {
    const float* inp = (const float*)d_in[0];   // (1,3,256,256)
    const float* ker = (const float*)d_in[1];   // (19,19,256,256)
    float* out = (float*)d_out;                 // (1,1,256,256)
    const float* in2 = inp + 2 * NPIX;          // channel 2

    float* rcpS1 = (float*)d_ws;
    float* rcpS2 = rcpS1 + NPIX;
    float* flat2 = rcpS2 + NPIX;

    const size_t needed = ((size_t)2 * NPIX + (size_t)NPIX * KK) * sizeof(float);

    k_s1<<<NPIX / 256, 256, 0, stream>>>(ker, rcpS1);

    if (ws_size >= needed) {
        k_transpose<<<NPIX / TQ, 256, 0, stream>>>(ker, rcpS1, flat2, rcpS2);
        k_out<<<NPIX / 4, 256, 0, stream>>>(flat2, in2, out);
    } else {
        k_s2_fallback<<<NPIX / 4, 256, 0, stream>>>(ker, rcpS1, rcpS2);
        k_out_fallback<<<NPIX / 4, 256, 0, stream>>>(ker, rcpS1, rcpS2, in2, out);
    }
}

// Round 2
// 97.941 us; speedup vs baseline: 1.2985x; 1.2985x over previous
//
#include <hip/hip_runtime.h>

// Problem constants (hardcoded in the reference)
#define NPIX 65536   // 256*256 = 2^16
#define KK   361     // 19*19
#define LSZ  19
#define HWD  256
#define NSTRIP 8
#define SPST 46      // rows of s per strip (ceil(361/8)); last strip has 39

// ---------------------------------------------------------------------------
// P1a: partial column sums. grid = (NPIX/256, NSTRIP). Full occupancy.
// part[strip*NPIX + p] = sum_{s in strip} ker[s*NPIX + p]
// ---------------------------------------------------------------------------
__global__ __launch_bounds__(256) void k_s1a(const float* __restrict__ ker,
                                             float* __restrict__ part) {
    int p = blockIdx.x * blockDim.x + threadIdx.x;
    int strip = blockIdx.y;
    int s0 = strip * SPST;
    int s1 = s0 + SPST; if (s1 > KK) s1 = KK;
    const float* kp = ker + p + (size_t)s0 * NPIX;
    int n = s1 - s0;
    float a0 = 0.f, a1 = 0.f, a2 = 0.f, a3 = 0.f;
    int s = 0;
    for (; s + 4 <= n; s += 4) {
        a0 += kp[(size_t)(s + 0) * NPIX];
        a1 += kp[(size_t)(s + 1) * NPIX];
        a2 += kp[(size_t)(s + 2) * NPIX];
        a3 += kp[(size_t)(s + 3) * NPIX];
    }
    for (; s < n; ++s) a0 += kp[(size_t)s * NPIX];
    part[(size_t)strip * NPIX + p] = (a0 + a1) + (a2 + a3);
}

// P1b: rcpS1[p] = 1 / sum_strip part[strip][p]
__global__ __launch_bounds__(256) void k_s1b(const float* __restrict__ part,
                                             float* __restrict__ rcpS1) {
    int p = blockIdx.x * blockDim.x + threadIdx.x;
    float a = 0.f;
#pragma unroll
    for (int i = 0; i < NSTRIP; ++i) a += part[(size_t)i * NPIX + p];
    rcpS1[p] = 1.0f / a;
}

// ---------------------------------------------------------------------------
// Fallback single-kernel S1 (only if ws can't hold partials)
// ---------------------------------------------------------------------------
__global__ __launch_bounds__(256) void k_s1(const float* __restrict__ ker,
                                            float* __restrict__ rcpS1) {
    int p = blockIdx.x * blockDim.x + threadIdx.x;
    const float* kp = ker + p;
    float a0 = 0.f, a1 = 0.f, a2 = 0.f, a3 = 0.f;
    int s = 0;
    for (; s + 4 <= KK; s += 4) {
        a0 += kp[(size_t)(s + 0) * NPIX];
        a1 += kp[(size_t)(s + 1) * NPIX];
        a2 += kp[(size_t)(s + 2) * NPIX];
        a3 += kp[(size_t)(s + 3) * NPIX];
    }
    for (; s < KK; ++s) a0 += kp[(size_t)s * NPIX];
    rcpS1[p] = 1.0f / (a0 + a1 + a2 + a3);
}

// ---------------------------------------------------------------------------
// P3: fused  (a) scale by rcpS1[(q*K+t) & 0xFFFF]
//            (b) exact per-row sum -> rcpS2 (in-LDS, no atomics)
//            (c) scale by rcpS2[q]
//            (d) transpose N x K -> K x N:  flat2[t*N + q] = val
// One block = 32 consecutive rows q (a contiguous 46.2 KB slab of ker).
// ---------------------------------------------------------------------------
#define TQ 32
__global__ __launch_bounds__(256) void k_transpose(const float* __restrict__ ker,
                                                   const float* __restrict__ rcpS1,
                                                   float* __restrict__ flat2,
                                                   float* __restrict__ rcpS2) {
    __shared__ float tile[TQ * KK];   // 46,208 B
    __shared__ float rowrcp[TQ];
    const int tid = threadIdx.x;
    const int q0  = blockIdx.x * TQ;
    const int base = q0 * KK;

    for (int idx = tid; idx < TQ * KK; idx += 256) {
        int m = base + idx;
        tile[idx] = ker[m] * rcpS1[m & (NPIX - 1)];
    }
    __syncthreads();

    {
        int row = tid >> 3;
        int e0  = tid & 7;
        float acc = 0.f;
        for (int e = e0; e < KK; e += 8) acc += tile[row * KK + e];
        acc += __shfl_xor(acc, 1);
        acc += __shfl_xor(acc, 2);
        acc += __shfl_xor(acc, 4);
        if (e0 == 0) {
            float r = 1.0f / acc;
            rowrcp[row] = r;
            rcpS2[q0 + row] = r;
        }
    }
    __syncthreads();

    {
        int iq = tid & 31;
        int t0 = tid >> 5;   // 0..7
        float rr = rowrcp[iq];
        for (int t = t0; t < KK; t += 8) {
            flat2[(size_t)t * NPIX + q0 + iq] = tile[iq * KK + t] * rr;
        }
    }
}

// reflect-pad index (pad=9, size 256, mode="reflect" no edge repeat)
__device__ __forceinline__ int refl(int v) {
    v -= 9;
    v = v < 0 ? -v : v;
    v = v > 255 ? 510 - v : v;
    return v;
}

// ---------------------------------------------------------------------------
// P4: out[r] = (sum_u dg[r,u]*flat2[r*K+u]) / (sum_u flat2[r*K+u])
// One 64-lane wave per output row; 4 rows per 256-thread block.
// ---------------------------------------------------------------------------
__global__ __launch_bounds__(256) void k_out(const float* __restrict__ flat2,
                                             const float* __restrict__ in2,
                                             float* __restrict__ out) {
    int lane = threadIdx.x & 63;
    int r = blockIdx.x * 4 + (threadIdx.x >> 6);
    const float* row = flat2 + (size_t)r * KK;
    float vsum = 0.f, vdot = 0.f;
    for (int u = lane; u < KK; u += 64) {
        float v = row[u];
        int jj = r * KK + u;
        int s  = jj >> 16;
        int c  = jj & (NPIX - 1);
        int y = c >> 8, x = c & 255;
        int a = s / LSZ, b = s - a * LSZ;
        float d = in2[refl(y + a) * HWD + refl(x + b)];
        vsum += v;
        vdot += d * v;
    }
    for (int m = 1; m < 64; m <<= 1) {
        vsum += __shfl_xor(vsum, m);
        vdot += __shfl_xor(vdot, m);
    }
    if (lane == 0) out[r] = vdot / vsum;
}

// ---------------------------------------------------------------------------
// Fallback (ws too small to hold the 90.3 MB transpose): strided gathers.
// ---------------------------------------------------------------------------
__global__ __launch_bounds__(256) void k_s2_fallback(const float* __restrict__ ker,
                                                     const float* __restrict__ rcpS1,
                                                     float* __restrict__ rcpS2) {
    int lane = threadIdx.x & 63;
    int q = blockIdx.x * 4 + (threadIdx.x >> 6);
    int base = q * KK;
    float acc = 0.f;
    for (int t = lane; t < KK; t += 64)
        acc += ker[base + t] * rcpS1[(base + t) & (NPIX - 1)];
    for (int m = 1; m < 64; m <<= 1) acc += __shfl_xor(acc, m);
    if (lane == 0) rcpS2[q] = 1.0f / acc;
}

__global__ __launch_bounds__(256) void k_out_fallback(const float* __restrict__ ker,
                                                      const float* __restrict__ rcpS1,
                                                      const float* __restrict__ rcpS2,
                                                      const float* __restrict__ in2,
                                                      float* __restrict__ out) {
    int lane = threadIdx.x & 63;
    int r = blockIdx.x * 4 + (threadIdx.x >> 6);
    float vsum = 0.f, vdot = 0.f;
    for (int u = lane; u < KK; u += 64) {
        int jj = r * KK + u;
        int t  = jj >> 16;
        int q  = jj & (NPIX - 1);
        int m  = q * KK + t;
        float v = ker[m] * rcpS1[m & (NPIX - 1)] * rcpS2[q];
        int c = jj & (NPIX - 1);
        int y = c >> 8, x = c & 255;
        int a = t / LSZ, b = t - a * LSZ;
        float d = in2[refl(y + a) * HWD + refl(x + b)];
        vsum += v;
        vdot += d * v;
    }
    for (int mm = 1; mm < 64; mm <<= 1) {
        vsum += __shfl_xor(vsum, mm);
        vdot += __shfl_xor(vdot, mm);
    }
    if (lane == 0) out[r] = vdot / vsum;
}

extern "C" void kernel_launch(void* const* d_in, const int* in_sizes, int n_in,
                              void* d_out, int out_size, void* d_ws, size_t ws_size,
                              hipStream_t stream) {
    const float* inp = (const float*)d_in[0];   // (1,3,256,256)
    const float* ker = (const float*)d_in[1];   // (19,19,256,256)
    float* out = (float*)d_out;                 // (1,1,256,256)
    const float* in2 = inp + 2 * NPIX;          // channel 2

    float* rcpS1 = (float*)d_ws;
    float* rcpS2 = rcpS1 + NPIX;
    float* flat2 = rcpS2 + NPIX;
    float* part  = flat2 + (size_t)NPIX * KK;

    const size_t needed  = ((size_t)2 * NPIX + (size_t)NPIX * KK) * sizeof(float);
    const size_t needed2 = needed + (size_t)NSTRIP * NPIX * sizeof(float);

    if (ws_size >= needed2) {
        dim3 g(NPIX / 256, NSTRIP);
        k_s1a<<<g, 256, 0, stream>>>(ker, part);
        k_s1b<<<NPIX / 256, 256, 0, stream>>>(part, rcpS1);
    } else {
        k_s1<<<NPIX / 256, 256, 0, stream>>>(ker, rcpS1);
    }

    if (ws_size >= needed) {
        k_transpose<<<NPIX / TQ, 256, 0, stream>>>(ker, rcpS1, flat2, rcpS2);
        k_out<<<NPIX / 4, 256, 0, stream>>>(flat2, in2, out);
    } else {
        k_s2_fallback<<<NPIX / 4, 256, 0, stream>>>(ker, rcpS1, rcpS2);
        k_out_fallback<<<NPIX / 4, 256, 0, stream>>>(ker, rcpS1, rcpS2, in2, out);
    }
}

// Round 3
// 74.062 us; speedup vs baseline: 1.7172x; 1.3224x over previous
//
#include <hip/hip_runtime.h>

// Problem constants (hardcoded in the reference)
#define NPIX 65536   // 256*256 = 2^16
#define KK   361     // 19*19
#define LSZ  19
#define HWD  256
#define NSTRIP 8
#define SPST 46      // s-rows per strip
#define QB   32      // q-rows per k_part block
#define NSLOT 16     // partial slots per output row (>= ceil(361/QB)+2)

// reflect-pad index (pad=9, size 256, mode="reflect")
__device__ __forceinline__ int refl(int v) {
    v -= 9;
    v = v < 0 ? -v : v;
    v = v > 255 ? 510 - v : v;
    return v;
}

// ---------------------------------------------------------------------------
// zero the partial buffer (poisoned 0xAA by harness)
// ---------------------------------------------------------------------------
__global__ __launch_bounds__(256) void k_zero(float4* __restrict__ p, int n4) {
    int i = blockIdx.x * 256 + threadIdx.x;
    if (i < n4) p[i] = float4{0.f, 0.f, 0.f, 0.f};
}

// ---------------------------------------------------------------------------
// P1a: partial column sums. grid = (NPIX/256, NSTRIP).
// ---------------------------------------------------------------------------
__global__ __launch_bounds__(256) void k_s1a(const float* __restrict__ ker,
                                             float* __restrict__ part) {
    int p = blockIdx.x * blockDim.x + threadIdx.x;
    int strip = blockIdx.y;
    int s0 = strip * SPST;
    int s1 = s0 + SPST; if (s1 > KK) s1 = KK;
    const float* kp = ker + p + (size_t)s0 * NPIX;
    int n = s1 - s0;
    float a0 = 0.f, a1 = 0.f, a2 = 0.f, a3 = 0.f;
    int s = 0;
    for (; s + 4 <= n; s += 4) {
        a0 += kp[(size_t)(s + 0) * NPIX];
        a1 += kp[(size_t)(s + 1) * NPIX];
        a2 += kp[(size_t)(s + 2) * NPIX];
        a3 += kp[(size_t)(s + 3) * NPIX];
    }
    for (; s < n; ++s) a0 += kp[(size_t)s * NPIX];
    part[(size_t)strip * NPIX + p] = (a0 + a1) + (a2 + a3);
}

// P1b: rcpS1[p] = 1 / sum_strip part[strip][p]
__global__ __launch_bounds__(256) void k_s1b(const float* __restrict__ part,
                                             float* __restrict__ rcpS1) {
    int p = blockIdx.x * blockDim.x + threadIdx.x;
    float a = 0.f;
#pragma unroll
    for (int i = 0; i < NSTRIP; ++i) a += part[(size_t)i * NPIX + p];
    rcpS1[p] = 1.0f / a;
}

// ---------------------------------------------------------------------------
// k_part: the fused transpose-free main pass.
// Block = 32 consecutive q-rows of ker (contiguous 46.2 KB slab -> LDS,
// scaled by rcpS1 on load). rcpS2 computed in-block. Then lane = t (0..360):
// walk q; j = t*65536 + q; r = j/361 is piecewise-constant with <=1 boundary
// per 32-chunk, so each lane register-accumulates (dot,sum) for <=2 rows and
// stores to partial[r][blockIdx & 15]. No atomics, no cross-lane reduce.
// ---------------------------------------------------------------------------
__global__ __launch_bounds__(384) void k_part(const float* __restrict__ ker,
                                              const float* __restrict__ rcpS1,
                                              const float* __restrict__ in2,
                                              float2* __restrict__ partial) {
    __shared__ float tile[QB * KK];   // 46,208 B
    __shared__ float rcpS2s[QB];
    const int tid = threadIdx.x;
    const int q0  = blockIdx.x * QB;
    const int base = q0 * KK;         // max ~23.6M, int ok; %4 == 0

    // stage slab -> LDS, scaled by rcpS1 (both reads coalesced float4)
    const float4* k4 = (const float4*)(ker + base);
    for (int i = tid; i < (QB * KK) / 4; i += 384) {
        float4 v = k4[i];
        int m = base + i * 4;
        const float4 s = *(const float4*)(rcpS1 + (m & (NPIX - 1)));
        v.x *= s.x; v.y *= s.y; v.z *= s.z; v.w *= s.w;
        *(float4*)(tile + i * 4) = v;
    }
    __syncthreads();

    // per-q row sums -> rcpS2s (wave w handles rows w, w+6, ...)
    {
        int wave = tid >> 6, lane = tid & 63;
        for (int qq = wave; qq < QB; qq += 6) {
            float a = 0.f;
            for (int e = lane; e < KK; e += 64) a += tile[qq * KK + e];
            for (int m = 1; m < 64; m <<= 1) a += __shfl_xor(a, m);
            if (lane == 0) rcpS2s[qq] = 1.0f / a;
        }
    }
    __syncthreads();

    if (tid < KK) {
        const int t  = tid;
        const int j0 = t * NPIX + q0;          // < 2^25
        const int r0 = j0 / KK;
        const int jm = j0 - r0 * KK;           // j0 % 361
        const int d0 = (jm == 0) ? 0 : (KK - jm);
        const int split = (d0 == 0 || d0 >= QB) ? QB : d0;
        const int a = t / LSZ, b = t - LSZ * a;
        float accAd = 0.f, accAs = 0.f, accBd = 0.f, accBs = 0.f;
#pragma unroll 8
        for (int off = 0; off < QB; ++off) {
            int q = q0 + off;
            float v = tile[off * KK + t] * rcpS2s[off];  // stride-1 lanes: no conflict
            int y = q >> 8, x = q & 255;
            float d = in2[refl(y + a) * HWD + refl(x + b)];
            float dv = d * v;
            bool inA = off < split;
            accAd += inA ? dv : 0.f;
            accAs += inA ? v  : 0.f;
            accBd += inA ? 0.f : dv;
            accBs += inA ? 0.f : v;
        }
        const int slot = blockIdx.x & (NSLOT - 1);
        partial[(size_t)r0 * NSLOT + slot] = float2{accAd, accAs};
        if (split < QB)
            partial[(size_t)(r0 + 1) * NSLOT + slot] = float2{accBd, accBs};
    }
}

// ---------------------------------------------------------------------------
// k_out2: out[r] = sum(dot slots) / sum(sum slots)
// ---------------------------------------------------------------------------
__global__ __launch_bounds__(256) void k_out2(const float2* __restrict__ partial,
                                              float* __restrict__ out) {
    int r = blockIdx.x * 256 + threadIdx.x;
    const float2* p = partial + (size_t)r * NSLOT;
    float dot = 0.f, sum = 0.f;
#pragma unroll
    for (int i = 0; i < NSLOT; ++i) { dot += p[i].x; sum += p[i].y; }
    out[r] = dot / sum;
}

// ---------------------------------------------------------------------------
// Minimal fallback path (tiny ws): direct strided gathers.
// ---------------------------------------------------------------------------
__global__ __launch_bounds__(256) void k_s1(const float* __restrict__ ker,
                                            float* __restrict__ rcpS1) {
    int p = blockIdx.x * blockDim.x + threadIdx.x;
    const float* kp = ker + p;
    float a = 0.f;
    for (int s = 0; s < KK; ++s) a += kp[(size_t)s * NPIX];
    rcpS1[p] = 1.0f / a;
}

__global__ __launch_bounds__(256) void k_s2_fallback(const float* __restrict__ ker,
                                                     const float* __restrict__ rcpS1,
                                                     float* __restrict__ rcpS2) {
    int lane = threadIdx.x & 63;
    int q = blockIdx.x * 4 + (threadIdx.x >> 6);
    int base = q * KK;
    float acc = 0.f;
    for (int t = lane; t < KK; t += 64)
        acc += ker[base + t] * rcpS1[(base + t) & (NPIX - 1)];
    for (int m = 1; m < 64; m <<= 1) acc += __shfl_xor(acc, m);
    if (lane == 0) rcpS2[q] = 1.0f / acc;
}

__global__ __launch_bounds__(256) void k_out_fallback(const float* __restrict__ ker,
                                                      const float* __restrict__ rcpS1,
                                                      const float* __restrict__ rcpS2,
                                                      const float* __restrict__ in2,
                                                      float* __restrict__ out) {
    int lane = threadIdx.x & 63;
    int r = blockIdx.x * 4 + (threadIdx.x >> 6);
    float vsum = 0.f, vdot = 0.f;
    for (int u = lane; u < KK; u += 64) {
        int jj = r * KK + u;
        int t  = jj >> 16;
        int q  = jj & (NPIX - 1);
        int m  = q * KK + t;
        float v = ker[m] * rcpS1[m & (NPIX - 1)] * rcpS2[q];
        int y = q >> 8, x = q & 255;
        int a = t / LSZ, b = t - a * LSZ;
        float d = in2[refl(y + a) * HWD + refl(x + b)];
        vsum += v;
        vdot += d * v;
    }
    for (int mm = 1; mm < 64; mm <<= 1) {
        vsum += __shfl_xor(vsum, mm);
        vdot += __shfl_xor(vdot, mm);
    }
    if (lane == 0) out[r] = vdot / vsum;
}

extern "C" void kernel_launch(void* const* d_in, const int* in_sizes, int n_in,
                              void* d_out, int out_size, void* d_ws, size_t ws_size,
                              hipStream_t stream) {
    const float* inp = (const float*)d_in[0];   // (1,3,256,256)
    const float* ker = (const float*)d_in[1];   // (19,19,256,256)
    float* out = (float*)d_out;                 // (1,1,256,256)
    const float* in2 = inp + 2 * NPIX;          // channel 2

    float*  rcpS1   = (float*)d_ws;                       // NPIX
    float*  s1part  = rcpS1 + NPIX;                       // NSTRIP*NPIX
    float2* partial = (float2*)(s1part + (size_t)NSTRIP * NPIX);  // NPIX*NSLOT float2

    const size_t needed = ((size_t)NPIX * (1 + NSTRIP) +
                           (size_t)NPIX * NSLOT * 2) * sizeof(float);  // ~10.75 MB

    if (ws_size >= needed) {
        const int n4 = NPIX * NSLOT * 2 / 4;              // 524288 float4
        k_zero<<<(n4 + 255) / 256, 256, 0, stream>>>((float4*)partial, n4);
        dim3 g(NPIX / 256, NSTRIP);
        k_s1a<<<g, 256, 0, stream>>>(ker, s1part);
        k_s1b<<<NPIX / 256, 256, 0, stream>>>(s1part, rcpS1);
        k_part<<<NPIX / QB, 384, 0, stream>>>(ker, rcpS1, in2, partial);
        k_out2<<<NPIX / 256, 256, 0, stream>>>(partial, out);
    } else {
        float* rcpS2 = rcpS1 + NPIX;   // needs only 512 KB total
        k_s1<<<NPIX / 256, 256, 0, stream>>>(ker, rcpS1);
        k_s2_fallback<<<NPIX / 4, 256, 0, stream>>>(ker, rcpS1, rcpS2);
        k_out_fallback<<<NPIX / 4, 256, 0, stream>>>(ker, rcpS1, rcpS2, in2, out);
    }
}

// Round 4
// 69.077 us; speedup vs baseline: 1.8411x; 1.0722x over previous
//
#include <hip/hip_runtime.h>

// Problem constants (hardcoded in the reference)
#define NPIX 65536   // 256*256 = 2^16
#define KK   361     // 19*19
#define LSZ  19
#define HWD  256
#define QB   32      // q-rows per k_part block
#define NBLK (NPIX / QB)          // 2048 k_part blocks
#define NSLOT 16     // partial slots per output row (window <= 13)
#define NS2  16      // s-strips for S1
#define SPS2 23      // s-rows per strip (last strip: 361 - 15*23 = 16)
#define DTC  50      // in2 LDS tile cols = QB-1 + LSZ

// reflect-pad index (pad=9, size 256, mode="reflect"); arg is (coord + offset)
__device__ __forceinline__ int refl(int v) {
    v -= 9;
    v = v < 0 ? -v : v;
    v = v > 255 ? 510 - v : v;
    return v;
}

// ---------------------------------------------------------------------------
// S1a: partial column sums, contiguous float4 reads.
// grid (64 p-windows, NS2 strips) x 256 thr. Each thread: one float4 acc.
// part4[strip*16384 + p4] = sum_{s in strip} ker4[s*16384 + p4]
// ---------------------------------------------------------------------------
__global__ __launch_bounds__(256) void k_s1a(const float4* __restrict__ ker4,
                                             float4* __restrict__ part4) {
    const int p4 = blockIdx.x * 256 + threadIdx.x;   // [0, 16384)
    const int strip = blockIdx.y;
    const int s0 = strip * SPS2;
    const int n = (strip == NS2 - 1) ? (KK - s0) : SPS2;
    const float4* kp = ker4 + (size_t)s0 * (NPIX / 4) + p4;
    float4 acc = {0.f, 0.f, 0.f, 0.f};
#pragma unroll 8
    for (int s = 0; s < n; ++s) {
        float4 v = kp[(size_t)s * (NPIX / 4)];
        acc.x += v.x; acc.y += v.y; acc.z += v.z; acc.w += v.w;
    }
    part4[(size_t)strip * (NPIX / 4) + p4] = acc;
}

// S1b: rcpS1[p] = 1 / sum_strips
__global__ __launch_bounds__(256) void k_s1b(const float4* __restrict__ part4,
                                             float4* __restrict__ rcp4) {
    const int i = blockIdx.x * 256 + threadIdx.x;    // [0, 16384)
    float4 a = {0.f, 0.f, 0.f, 0.f};
#pragma unroll
    for (int s = 0; s < NS2; ++s) {
        float4 v = part4[(size_t)s * (NPIX / 4) + i];
        a.x += v.x; a.y += v.y; a.z += v.z; a.w += v.w;
    }
    rcp4[i] = float4{1.0f / a.x, 1.0f / a.y, 1.0f / a.z, 1.0f / a.w};
}

// ---------------------------------------------------------------------------
// k_part: block = 32 consecutive q-rows of ker (46.2 KB contiguous -> LDS,
// scaled by rcpS1). rcpS2 per-row in-block. in2 footprint per block is a
// single 19x50 patch (y = q>>8 constant) -> staged reflected into LDS.
// Main loop: lane = t; j = t*65536 + q walks; r = j/361 piecewise-constant
// with <=1 boundary per 32-chunk -> register accumulation, <=2 partial
// stores per lane to partial[r][blockIdx & 15]. No atomics, no zeroing.
// ---------------------------------------------------------------------------
__global__ __launch_bounds__(384) void k_part(const float* __restrict__ ker,
                                              const float* __restrict__ rcpS1,
                                              const float* __restrict__ in2,
                                              float2* __restrict__ partial) {
    __shared__ float tile[QB * KK];      // 46,208 B
    __shared__ float dt[LSZ * DTC];      // 3,800 B
    __shared__ float rcpS2s[QB];
    const int tid = threadIdx.x;
    const int q0  = blockIdx.x * QB;
    const int base = q0 * KK;            // < 2^25, %4 == 0

    // stage ker slab (coalesced float4), scaled by rcpS1
    const float4* k4 = (const float4*)(ker + base);
    for (int i = tid; i < (QB * KK) / 4; i += 384) {
        float4 v = k4[i];
        int m = base + i * 4;
        const float4 s = *(const float4*)(rcpS1 + (m & (NPIX - 1)));
        v.x *= s.x; v.y *= s.y; v.z *= s.z; v.w *= s.w;
        *(float4*)(tile + i * 4) = v;
    }
    // stage reflected in2 patch: y0 constant per block (QB | 256)
    {
        const int y0 = q0 >> 8, x0 = q0 & 255;
        for (int i = tid; i < LSZ * DTC; i += 384) {
            int a = i / DTC, c = i - a * DTC;
            dt[i] = in2[refl(y0 + a) * HWD + refl(x0 + c)];
        }
    }
    __syncthreads();

    // per-q row sums -> rcpS2s
    {
        int wave = tid >> 6, lane = tid & 63;
        for (int qq = wave; qq < QB; qq += 6) {
            float a = 0.f;
            for (int e = lane; e < KK; e += 64) a += tile[qq * KK + e];
            for (int m = 1; m < 64; m <<= 1) a += __shfl_xor(a, m);
            if (lane == 0) rcpS2s[qq] = 1.0f / a;
        }
    }
    __syncthreads();

    if (tid < KK) {
        const int t  = tid;
        const int j0 = t * NPIX + q0;
        const int r0 = j0 / KK;
        const int jm = j0 - r0 * KK;
        const int d0 = (jm == 0) ? 0 : (KK - jm);
        const int split = (d0 == 0 || d0 >= QB) ? QB : d0;
        const int a = t / LSZ, b = t - LSZ * a;
        const int dbase = a * DTC + b;
        float accAd = 0.f, accAs = 0.f, accBd = 0.f, accBs = 0.f;
#pragma unroll 8
        for (int off = 0; off < QB; ++off) {
            float v = tile[off * KK + t] * rcpS2s[off];
            float d = dt[dbase + off];
            float dv = d * v;
            bool inA = off < split;
            accAd += inA ? dv : 0.f;
            accAs += inA ? v  : 0.f;
            accBd += inA ? 0.f : dv;
            accBs += inA ? 0.f : v;
        }
        const int slot = blockIdx.x & (NSLOT - 1);
        partial[(size_t)r0 * NSLOT + slot] = float2{accAd, accAs};
        if (split < QB)
            partial[(size_t)(r0 + 1) * NSLOT + slot] = float2{accBd, accBs};
    }
}

// ---------------------------------------------------------------------------
// k_out2: sum exactly the valid slot window for row r (no zero-init needed).
// Blocks touching row r: bx in [qs>>5 .. ql>>5] (mod NBLK), <= 13 wide;
// slots = bx & 15, distinct since window < 16 and 16 | NBLK.
// ---------------------------------------------------------------------------
__global__ __launch_bounds__(256) void k_out2(const float2* __restrict__ partial,
                                              float* __restrict__ out) {
    const int r = blockIdx.x * 256 + threadIdx.x;
    const int j0 = r * KK;
    const int qs = j0 & (NPIX - 1);
    const int ql = (j0 + KK - 1) & (NPIX - 1);
    const int first = qs >> 5;
    const int last  = ql >> 5;
    const int cnt = ((last - first) & (NBLK - 1)) + 1;
    const float2* p = partial + (size_t)r * NSLOT;
    float dot = 0.f, sum = 0.f;
    for (int i = 0; i < cnt; ++i) {
        float2 v = p[(first + i) & (NSLOT - 1)];
        dot += v.x; sum += v.y;
    }
    out[r] = dot / sum;
}

// ---------------------------------------------------------------------------
// Minimal fallback path (tiny ws): direct strided gathers.
// ---------------------------------------------------------------------------
__global__ __launch_bounds__(256) void k_s1(const float* __restrict__ ker,
                                            float* __restrict__ rcpS1) {
    int p = blockIdx.x * blockDim.x + threadIdx.x;
    const float* kp = ker + p;
    float a = 0.f;
    for (int s = 0; s < KK; ++s) a += kp[(size_t)s * NPIX];
    rcpS1[p] = 1.0f / a;
}

__global__ __launch_bounds__(256) void k_s2_fallback(const float* __restrict__ ker,
                                                     const float* __restrict__ rcpS1,
                                                     float* __restrict__ rcpS2) {
    int lane = threadIdx.x & 63;
    int q = blockIdx.x * 4 + (threadIdx.x >> 6);
    int base = q * KK;
    float acc = 0.f;
    for (int t = lane; t < KK; t += 64)
        acc += ker[base + t] * rcpS1[(base + t) & (NPIX - 1)];
    for (int m = 1; m < 64; m <<= 1) acc += __shfl_xor(acc, m);
    if (lane == 0) rcpS2[q] = 1.0f / acc;
}

__global__ __launch_bounds__(256) void k_out_fallback(const float* __restrict__ ker,
                                                      const float* __restrict__ rcpS1,
                                                      const float* __restrict__ rcpS2,
                                                      const float* __restrict__ in2,
                                                      float* __restrict__ out) {
    int lane = threadIdx.x & 63;
    int r = blockIdx.x * 4 + (threadIdx.x >> 6);
    float vsum = 0.f, vdot = 0.f;
    for (int u = lane; u < KK; u += 64) {
        int jj = r * KK + u;
        int t  = jj >> 16;
        int q  = jj & (NPIX - 1);
        int m  = q * KK + t;
        float v = ker[m] * rcpS1[m & (NPIX - 1)] * rcpS2[q];
        int y = q >> 8, x = q & 255;
        int a = t / LSZ, b = t - a * LSZ;
        float d = in2[refl(y + a) * HWD + refl(x + b)];
        vsum += v;
        vdot += d * v;
    }
    for (int mm = 1; mm < 64; mm <<= 1) {
        vsum += __shfl_xor(vsum, mm);
        vdot += __shfl_xor(vdot, mm);
    }
    if (lane == 0) out[r] = vdot / vsum;
}

extern "C" void kernel_launch(void* const* d_in, const int* in_sizes, int n_in,
                              void* d_out, int out_size, void* d_ws, size_t ws_size,
                              hipStream_t stream) {
    const float* inp = (const float*)d_in[0];   // (1,3,256,256)
    const float* ker = (const float*)d_in[1];   // (19,19,256,256)
    float* out = (float*)d_out;                 // (1,1,256,256)
    const float* in2 = inp + 2 * NPIX;          // channel 2

    float*  rcpS1   = (float*)d_ws;                           // NPIX
    float*  s1part  = rcpS1 + NPIX;                           // NS2*NPIX
    float2* partial = (float2*)(s1part + (size_t)NS2 * NPIX); // NPIX*NSLOT float2

    const size_t needed = ((size_t)NPIX * (1 + NS2) +
                           (size_t)NPIX * NSLOT * 2) * sizeof(float);  // ~12.25 MB

    if (ws_size >= needed) {
        dim3 g1(NPIX / 4 / 256, NS2);   // (64, 16)
        k_s1a<<<g1, 256, 0, stream>>>((const float4*)ker, (float4*)s1part);
        k_s1b<<<NPIX / 4 / 256, 256, 0, stream>>>((const float4*)s1part, (float4*)rcpS1);
        k_part<<<NBLK, 384, 0, stream>>>(ker, rcpS1, in2, partial);
        k_out2<<<NPIX / 256, 256, 0, stream>>>(partial, out);
    } else {
        float* rcpS2 = rcpS1 + NPIX;   // fallback needs only 512 KB
        k_s1<<<NPIX / 256, 256, 0, stream>>>(ker, rcpS1);
        k_s2_fallback<<<NPIX / 4, 256, 0, stream>>>(ker, rcpS1, rcpS2);
        k_out_fallback<<<NPIX / 4, 256, 0, stream>>>(ker, rcpS1, rcpS2, in2, out);
    }
}